// Round 3
// baseline (64993.140 us; speedup 1.0000x reference)
//
#include <hip/hip_runtime.h>
#include <cstdint>
#include <cstddef>

typedef _Float16 f16;
typedef _Float16 f16x2 __attribute__((ext_vector_type(2)));
typedef _Float16 f16x4 __attribute__((ext_vector_type(4)));
typedef _Float16 f16x8 __attribute__((ext_vector_type(8)));

#define S_LEN 2048
#define BATCH 64
#define I_DIM 128
#define H_DIM 512
#define O_DIM 64

// hbuf: 2 buffers x 64 batches x 512 f16 = 131072 B, lives at d_out[0].
// flags: 256 ints, one per (batch,wg), 64B stride = 16 KB, after hbuf.
#define HBUF_F16S (2 * BATCH * H_DIM)
#define HBUF_BYTES (HBUF_F16S * 2)
#define NFLAGS (BATCH * 4)

__device__ __forceinline__ float fdot2f(f16x2 a, f16x2 b, float c) {
#if __has_builtin(__builtin_amdgcn_fdot2)
    return __builtin_amdgcn_fdot2(a, b, c, false);
#else
    return c + (float)a.x * (float)b.x + (float)a.y * (float)b.y;
#endif
}

// ---------------------------------------------------------------------------
// Phase 0: zero the flag region (d_out is re-poisoned to 0xAA every launch).
// ---------------------------------------------------------------------------
__global__ void flag_init_kernel(int* __restrict__ flags) {
    int i = blockIdx.x * blockDim.x + threadIdx.x;
    if (i < NFLAGS * 16) flags[i] = 0;
}

// ---------------------------------------------------------------------------
// Phase 1: u[row][c] = sum_k x[row][k] * Wih[k][c], rows = B*S, K=128, N=512.
// ---------------------------------------------------------------------------
__global__ __launch_bounds__(256)
void u_gemm_kernel(const float* __restrict__ x, const float* __restrict__ Wih,
                   f16* __restrict__ u) {
    const int tid = threadIdx.x;
    const int r0 = blockIdx.x * 32;
    const int c0 = blockIdx.y * 128;

    __shared__ __align__(16) f16x2 wih_s[I_DIM / 2][128];
    __shared__ __align__(16) f16x2 x_s[32][I_DIM / 2];

#pragma unroll
    for (int i = 0; i < 32; ++i) {
        int idx = i * 256 + tid;
        int kp = idx >> 7;
        int cl = idx & 127;
        float w0 = Wih[(size_t)(2 * kp + 0) * H_DIM + c0 + cl];
        float w1 = Wih[(size_t)(2 * kp + 1) * H_DIM + c0 + cl];
        f16x2 w; w.x = (f16)w0; w.y = (f16)w1;
        wih_s[kp][cl] = w;
    }
    const float4* xs = (const float4*)(x + (size_t)r0 * I_DIM);
    f16x4* xd = (f16x4*)x_s;
#pragma unroll
    for (int i = 0; i < 4; ++i) {
        int idx = i * 256 + tid;
        float4 v = xs[idx];
        f16x4 h; h.x = (f16)v.x; h.y = (f16)v.y; h.z = (f16)v.z; h.w = (f16)v.w;
        xd[idx] = h;
    }
    __syncthreads();

    const int cl = tid & 127;
    const int rh = tid >> 7;
    float acc[16];
#pragma unroll
    for (int r = 0; r < 16; ++r) acc[r] = 0.f;

#pragma unroll
    for (int kc = 0; kc < 2; ++kc) {
        f16x2 wv[32];
#pragma unroll
        for (int i = 0; i < 32; ++i) wv[i] = wih_s[kc * 32 + i][cl];
#pragma unroll
        for (int r = 0; r < 16; ++r) {
            const int row = rh * 16 + r;
#pragma unroll
            for (int m = 0; m < 8; ++m) {
                f16x8 h8 = *(const f16x8*)(&x_s[row][kc * 32 + 4 * m]);
                const f16x2* hp = (const f16x2*)&h8;
                acc[r] = fdot2f(wv[4 * m + 0], hp[0], acc[r]);
                acc[r] = fdot2f(wv[4 * m + 1], hp[1], acc[r]);
                acc[r] = fdot2f(wv[4 * m + 2], hp[2], acc[r]);
                acc[r] = fdot2f(wv[4 * m + 3], hp[3], acc[r]);
            }
        }
    }
#pragma unroll
    for (int r = 0; r < 16; ++r) {
        int row = r0 + rh * 16 + r;
        u[(size_t)row * H_DIM + c0 + cl] = (f16)acc[r];
    }
}

// ---------------------------------------------------------------------------
// Phase 2: scan split 4 ways per batch. 256 WGs x 512 threads, one per CU.
// blockIdx = w*64 + b (peers of batch b are {b, b+64, b+128, b+192}: same
// XCD under round-robin %8 mapping -> L2-local handoff).
// WG (b,w) owns columns [w*128, w*128+128). Thread (kq=tid&7, cq=tid>>3)
// owns columns c0=w*128+2*cq, c0+1 over k-slice [kq*64, kq*64+64).
// W: 64 f16x2 VGPRs/thread, fully register-resident. h exchanged through
// double-buffered global hbuf (L2) with per-WG flags (release/acquire,
// agent scope). 3-round packed-f16 butterfly reduces the 8 k-groups.
// ---------------------------------------------------------------------------
__global__ __launch_bounds__(512, 2)
void rnn_scan_kernel(const float* __restrict__ Wrec, f16* __restrict__ uhs,
                     f16* __restrict__ hbuf, int* __restrict__ flags) {
    const int tid = threadIdx.x;
    const int b = blockIdx.x & 63;
    const int w = blockIdx.x >> 6;
    const int kq = tid & 7;
    const int cq = tid >> 3;
    const int k0 = kq * 64;
    const int c0 = w * 128 + 2 * cq;
    const int myblk = kq >> 1;                 // which wg's h-block my slice is in
    const bool is_owner = (kq == 0);
    const bool need_poll = (myblk != w);

    // ---- W columns c0, c0+1 as k-pairs: 64 VGPRs ----
    f16x2 w0[32], w1[32];
#pragma unroll
    for (int q = 0; q < 32; ++q) {
        const float* rA = Wrec + (size_t)(k0 + 2 * q) * H_DIM + c0;
        const float* rB = Wrec + (size_t)(k0 + 2 * q + 1) * H_DIM + c0;
        f16x2 a; a.x = (f16)rA[0]; a.y = (f16)rB[0];
        f16x2 c; c.x = (f16)rA[1]; c.y = (f16)rB[1];
        w0[q] = a; w1[q] = c;
    }

    f16* hb0 = hbuf + b * H_DIM;               // buffer 0
    f16* hb1 = hbuf + BATCH * H_DIM + b * H_DIM; // buffer 1
    int* myflag   = flags + (b * 4 + w) * 16;
    const int* peerflag = flags + (b * 4 + myblk) * 16;

    f16* io = uhs + (size_t)b * S_LEN * H_DIM + c0;   // u in / hs out (in-place)
    float h0p = 0.f, h1p = 0.f;                // fp32 h_prev for own 2 columns
    f16x2 u_cur;
    u_cur.x = (f16)0.f; u_cur.y = (f16)0.f;
    if (is_owner) u_cur = *(const f16x2*)io;

    for (int t = 0; t < S_LEN; ++t) {
        // prefetch next u early (owners only)
        f16x2 u_nx; u_nx.x = (f16)0.f; u_nx.y = (f16)0.f;
        if (is_owner && t + 1 < S_LEN) u_nx = *(const f16x2*)(io + H_DIM);

        float a0 = 0.f, a1 = 0.f;
        if (t > 0) {
            if (need_poll) {
                while (__hip_atomic_load(peerflag, __ATOMIC_ACQUIRE,
                                         __HIP_MEMORY_SCOPE_AGENT) < t) { }
            }
            const f16x8* hsl = (const f16x8*)(((t & 1) ? hb1 : hb0) + k0);
#pragma unroll
            for (int g = 0; g < 8; ++g) {
                f16x8 hv = hsl[g];
                const f16x2* hp = (const f16x2*)&hv;
#pragma unroll
                for (int p = 0; p < 4; ++p) {
                    a0 = fdot2f(w0[g * 4 + p], hp[p], a0);
                    a1 = fdot2f(w1[g * 4 + p], hp[p], a1);
                }
            }
            // butterfly-reduce the 8 k-groups (lanes kq=0..7, consecutive)
            f16x2 v; v.x = (f16)a0; v.y = (f16)a1;
#define SWZ_ADD(vv, IMM)                                                      \
            {                                                                 \
                int s_ = __builtin_amdgcn_ds_swizzle(                         \
                    __builtin_bit_cast(int, vv), IMM);                        \
                vv = vv + __builtin_bit_cast(f16x2, s_);                      \
            }
            SWZ_ADD(v, 0x041F)
            SWZ_ADD(v, 0x081F)
            SWZ_ADD(v, 0x101F)
#undef SWZ_ADD
            a0 = (float)v.x; a1 = (float)v.y;
        }

        if (is_owner) {
            float z0 = a0 + (float)u_cur.x;
            float z1 = a1 + (float)u_cur.y;
            // tanh(z) = 1 - 2/(exp(2z)+1); saturates correctly
            float r0 = 1.f - 2.f * __builtin_amdgcn_rcpf(__expf(2.f * z0) + 1.f);
            float r1 = 1.f - 2.f * __builtin_amdgcn_rcpf(__expf(2.f * z1) + 1.f);
            h0p = 0.8f * h0p + 0.2f * r0;
            h1p = 0.8f * h1p + 0.2f * r1;
            f16x2 hh; hh.x = (f16)h0p; hh.y = (f16)h1p;
            *(f16x2*)(((t & 1) ? hb0 : hb1) + c0) = hh;  // h(t+1) -> buffer (t+1)&1
            *(f16x2*)io = hh;                            // hs[b][t][c0..c0+1]
            u_cur = u_nx;
        }
        io += H_DIM;
        __syncthreads();   // drains vmcnt(0): all owners' stores complete
        if (tid == 0)
            __hip_atomic_store(myflag, t + 1, __ATOMIC_RELEASE,
                               __HIP_MEMORY_SCOPE_AGENT);
    }
}

// ---------------------------------------------------------------------------
// Phase 3: out[row][o] = sum_k hs[row][k] * Who[k][o], K=512, O=64, fp32 out.
// ---------------------------------------------------------------------------
__global__ __launch_bounds__(256)
void out_gemm_kernel(const f16* __restrict__ hs, const float* __restrict__ Who,
                     float* __restrict__ out) {
    const int tid = threadIdx.x;
    const int r0 = blockIdx.x * 32;

    __shared__ __align__(16) f16x2 who_s[128][O_DIM];
    __shared__ __align__(16) f16x2 hs_s[32][128];

    const int o = tid & 63;
    const int rg = tid >> 6;

    float acc[8];
#pragma unroll
    for (int r = 0; r < 8; ++r) acc[r] = 0.f;

    for (int kc = 0; kc < 2; ++kc) {
        if (kc) __syncthreads();
#pragma unroll
        for (int i = 0; i < 32; ++i) {
            int idx = i * 256 + tid;
            int kp = idx >> 6;
            int oc = idx & 63;
            float w0 = Who[(size_t)(kc * 256 + 2 * kp + 0) * O_DIM + oc];
            float w1 = Who[(size_t)(kc * 256 + 2 * kp + 1) * O_DIM + oc];
            f16x2 w; w.x = (f16)w0; w.y = (f16)w1;
            who_s[kp][oc] = w;
        }
        f16x8* hd = (f16x8*)hs_s;
#pragma unroll
        for (int i = 0; i < 4; ++i) {
            int idx = i * 256 + tid;
            int r = idx >> 5;
            int m = idx & 31;
            f16x8 v = *(const f16x8*)(hs + (size_t)(r0 + r) * H_DIM + kc * 256 + m * 8);
            hd[idx] = v;
        }
        __syncthreads();

#pragma unroll
        for (int sc = 0; sc < 4; ++sc) {
            f16x2 wv[32];
#pragma unroll
            for (int i = 0; i < 32; ++i) wv[i] = who_s[sc * 32 + i][o];
#pragma unroll
            for (int r = 0; r < 8; ++r) {
                const int row = rg * 8 + r;
#pragma unroll
                for (int m = 0; m < 8; ++m) {
                    f16x8 h8 = *(const f16x8*)(&hs_s[row][sc * 32 + 4 * m]);
                    const f16x2* hp = (const f16x2*)&h8;
                    acc[r] = fdot2f(wv[4 * m + 0], hp[0], acc[r]);
                    acc[r] = fdot2f(wv[4 * m + 1], hp[1], acc[r]);
                    acc[r] = fdot2f(wv[4 * m + 2], hp[2], acc[r]);
                    acc[r] = fdot2f(wv[4 * m + 3], hp[3], acc[r]);
                }
            }
        }
    }
#pragma unroll
    for (int r = 0; r < 8; ++r) {
        int row = r0 + rg * 8 + r;
        out[(size_t)row * O_DIM + o] = acc[r];
    }
}

extern "C" void kernel_launch(void* const* d_in, const int* in_sizes, int n_in,
                              void* d_out, int out_size, void* d_ws, size_t ws_size,
                              hipStream_t stream) {
    const float* x    = (const float*)d_in[0];   // [64][2048][128]
    const float* Wih  = (const float*)d_in[1];   // [128][512]
    const float* Wrec = (const float*)d_in[2];   // [512][512]
    const float* Who  = (const float*)d_in[3];   // [512][64]
    float* out = (float*)d_out;                  // [64][2048][64]
    f16* uhs = (f16*)d_ws;                       // 128 MB: u, then hs in-place

    // h-exchange buffers + flags live in the first 144 KB of d_out; phase 3
    // overwrites the whole region afterwards.
    f16* hbuf  = (f16*)d_out;
    int* flags = (int*)((char*)d_out + HBUF_BYTES);

    const int R = BATCH * S_LEN;

    flag_init_kernel<<<dim3((NFLAGS * 16 + 255) / 256), 256, 0, stream>>>(flags);
    u_gemm_kernel<<<dim3(R / 32, H_DIM / 128), 256, 0, stream>>>(x, Wih, uhs);
    rnn_scan_kernel<<<dim3(4 * BATCH), 512, 0, stream>>>(Wrec, uhs, hbuf, flags);
    out_gemm_kernel<<<dim3(R / 32), 256, 0, stream>>>(uhs, Who, out);
}

// Round 4
// 3575.608 us; speedup vs baseline: 18.1768x; 18.1768x over previous
//
#include <hip/hip_runtime.h>
#include <hip/hip_fp16.h>
#include <cstdint>
#include <cstddef>

typedef _Float16 f16;
typedef _Float16 f16x2 __attribute__((ext_vector_type(2)));
typedef _Float16 f16x4 __attribute__((ext_vector_type(4)));
typedef _Float16 f16x8 __attribute__((ext_vector_type(8)));

#define S_LEN 2048
#define BATCH 64
#define I_DIM 128
#define H_DIM 512
#define O_DIM 64

// v_dot2_f32_f16 (fp32 accumulate — used in the small GEMMs only).
__device__ __forceinline__ float fdot2f(f16x2 a, f16x2 b, float c) {
#if __has_builtin(__builtin_amdgcn_fdot2)
    return __builtin_amdgcn_fdot2(a, b, c, false);
#else
    return c + (float)a.x * (float)b.x + (float)a.y * (float)b.y;
#endif
}

// v_pk_fma_f16: full-rate packed f16 FMA (2 MACs / 2 cyc).
__device__ __forceinline__ f16x2 pkfma(f16x2 a, f16x2 b, f16x2 c) {
    __half2 r = __hfma2(__builtin_bit_cast(__half2, a),
                        __builtin_bit_cast(__half2, b),
                        __builtin_bit_cast(__half2, c));
    return __builtin_bit_cast(f16x2, r);
}

// DPP quad_perm cross-lane (xor1: 0xB1, xor2: 0x4E) — VALU, no LDS.
template <int CTRL>
__device__ __forceinline__ f16x2 dpp_qp(f16x2 v) {
    int r = __builtin_amdgcn_update_dpp(0, __builtin_bit_cast(int, v),
                                        CTRL, 0xF, 0xF, true);
    return __builtin_bit_cast(f16x2, r);
}

// ---------------------------------------------------------------------------
// Phase 1: u[row][c] = sum_k x[row][k] * Wih[k][c], rows = B*S, K=128, N=512.
// ---------------------------------------------------------------------------
__global__ __launch_bounds__(256)
void u_gemm_kernel(const float* __restrict__ x, const float* __restrict__ Wih,
                   f16* __restrict__ u) {
    const int tid = threadIdx.x;
    const int r0 = blockIdx.x * 32;
    const int c0 = blockIdx.y * 128;

    __shared__ __align__(16) f16x2 wih_s[I_DIM / 2][128];
    __shared__ __align__(16) f16x2 x_s[32][I_DIM / 2];

#pragma unroll
    for (int i = 0; i < 32; ++i) {
        int idx = i * 256 + tid;
        int kp = idx >> 7;
        int cl = idx & 127;
        float w0 = Wih[(size_t)(2 * kp + 0) * H_DIM + c0 + cl];
        float w1 = Wih[(size_t)(2 * kp + 1) * H_DIM + c0 + cl];
        f16x2 w; w.x = (f16)w0; w.y = (f16)w1;
        wih_s[kp][cl] = w;
    }
    const float4* xs = (const float4*)(x + (size_t)r0 * I_DIM);
    f16x4* xd = (f16x4*)x_s;
#pragma unroll
    for (int i = 0; i < 4; ++i) {
        int idx = i * 256 + tid;
        float4 v = xs[idx];
        f16x4 h; h.x = (f16)v.x; h.y = (f16)v.y; h.z = (f16)v.z; h.w = (f16)v.w;
        xd[idx] = h;
    }
    __syncthreads();

    const int cl = tid & 127;
    const int rh = tid >> 7;
    float acc[16];
#pragma unroll
    for (int r = 0; r < 16; ++r) acc[r] = 0.f;

#pragma unroll
    for (int kc = 0; kc < 2; ++kc) {
        f16x2 wv[32];
#pragma unroll
        for (int i = 0; i < 32; ++i) wv[i] = wih_s[kc * 32 + i][cl];
#pragma unroll
        for (int r = 0; r < 16; ++r) {
            const int row = rh * 16 + r;
#pragma unroll
            for (int m = 0; m < 8; ++m) {
                f16x8 h8 = *(const f16x8*)(&x_s[row][kc * 32 + 4 * m]);
                const f16x2* hp = (const f16x2*)&h8;
                acc[r] = fdot2f(wv[4 * m + 0], hp[0], acc[r]);
                acc[r] = fdot2f(wv[4 * m + 1], hp[1], acc[r]);
                acc[r] = fdot2f(wv[4 * m + 2], hp[2], acc[r]);
                acc[r] = fdot2f(wv[4 * m + 3], hp[3], acc[r]);
            }
        }
    }
#pragma unroll
    for (int r = 0; r < 16; ++r) {
        int row = r0 + rh * 16 + r;
        u[(size_t)row * H_DIM + c0 + cl] = (f16)acc[r];
    }
}

// ---------------------------------------------------------------------------
// Phase 2: split-K scan, one WG (512 threads) per batch element (CU-local:
// the R3 cross-CU variant lost 20x to agent-scope cache maintenance).
// Thread (kg=tid&7, cg=tid>>3) owns k-slice [kg*64,kg*64+64) of the 8
// columns c=i*64+cg. W cols 0..6 + col7 pairs 0..3 in VGPRs; col7 pairs
// 4..31 in LDS. Inner product via v_pk_fma_f16 (full rate; dot2_f32_f16
// measured ~fp32-FMA rate in R2). Cross-lane reduce: 1 ds_swizzle round
// (xor4) + 2 DPP quad_perm rounds (xor2, xor1) with progressive narrowing.
// ---------------------------------------------------------------------------
__global__ __launch_bounds__(512, 2)
void rnn_scan_kernel(const float* __restrict__ Wrec, f16* __restrict__ uhs) {
    const int tid = threadIdx.x;
    const int b = blockIdx.x;
    const int kg = tid & 7;
    const int cg = tid >> 3;
    const int k0 = kg * 64;

    __shared__ __align__(16) f16x8 w4[7][512];     // col7 pairs 4..31: 57344 B
    __shared__ __align__(16) f16 h_pad[2][8][72];  // 64 data + 8 pad: 2304 B

    // ---- W load: cols i*64+cg (i=0..6), 32 pairs each -> 224 VGPRs ----
    f16x2 wreg[7][32];
#pragma unroll
    for (int i = 0; i < 7; ++i)
#pragma unroll
        for (int p = 0; p < 32; ++p) {
            float a = Wrec[(size_t)(k0 + 2 * p + 0) * H_DIM + i * 64 + cg];
            float c = Wrec[(size_t)(k0 + 2 * p + 1) * H_DIM + i * 64 + cg];
            f16x2 w; w.x = (f16)a; w.y = (f16)c;
            wreg[i][p] = w;
        }
    f16x8 w7pack;   // col 448+cg, k = k0..k0+7 (pairs 0..3)
#pragma unroll
    for (int e = 0; e < 8; ++e)
        w7pack[e] = (f16)Wrec[(size_t)(k0 + e) * H_DIM + 448 + cg];
#pragma unroll
    for (int q = 0; q < 7; ++q) {
        f16x8 v;
#pragma unroll
        for (int e = 0; e < 8; ++e)
            v[e] = (f16)Wrec[(size_t)(k0 + 8 + 8 * q + e) * H_DIM + 448 + cg];
        w4[q][tid] = v;
    }
    if (tid < 576) ((f16*)h_pad)[tid] = (f16)0.f;   // zero h buffer 0
    __syncthreads();

    const int c_own = k0 + cg;
    f16* io = uhs + (size_t)b * S_LEN * H_DIM + c_own;
    float h_prev = 0.f;
    float u_cur = (float)io[0];

    const f16* hb0 = &h_pad[0][kg][0];
    const f16* hb1 = &h_pad[1][kg][0];

    for (int t = 0; t < S_LEN; ++t) {
        f16 u_next = (f16)0.f;
        if (t + 1 < S_LEN) u_next = io[(size_t)(t + 1) * H_DIM];

        const f16* hb = (t & 1) ? hb1 : hb0;
        f16x2 acc[8];
#pragma unroll
        for (int i = 0; i < 8; ++i) { acc[i].x = (f16)0.f; acc[i].y = (f16)0.f; }

#pragma unroll
        for (int g = 0; g < 8; ++g) {
            f16x8 hv = *(const f16x8*)(hb + g * 8);   // bank-staggered broadcast
            f16x8 w7v;
            if (g == 0) w7v = w7pack; else w7v = w4[g - 1][tid];
            const f16x2* hp = (const f16x2*)&hv;
            const f16x2* wp = (const f16x2*)&w7v;
#pragma unroll
            for (int p = 0; p < 4; ++p) {
                acc[0] = pkfma(wreg[0][g * 4 + p], hp[p], acc[0]);
                acc[1] = pkfma(wreg[1][g * 4 + p], hp[p], acc[1]);
                acc[2] = pkfma(wreg[2][g * 4 + p], hp[p], acc[2]);
                acc[3] = pkfma(wreg[3][g * 4 + p], hp[p], acc[3]);
                acc[4] = pkfma(wreg[4][g * 4 + p], hp[p], acc[4]);
                acc[5] = pkfma(wreg[5][g * 4 + p], hp[p], acc[5]);
                acc[6] = pkfma(wreg[6][g * 4 + p], hp[p], acc[6]);
                acc[7] = pkfma(wp[p], hp[p], acc[7]);
            }
        }

        // compress each column (even-k + odd-k halves) and pack column pairs
        f16x2 P0, P1, P2, P3;
        P0.x = acc[0].x + acc[0].y;  P0.y = acc[1].x + acc[1].y;
        P1.x = acc[2].x + acc[2].y;  P1.y = acc[3].x + acc[3].y;
        P2.x = acc[4].x + acc[4].y;  P2.y = acc[5].x + acc[5].y;
        P3.x = acc[6].x + acc[6].y;  P3.y = acc[7].x + acc[7].y;

        // round 1: xor4 via ds_swizzle, narrow 4 vecs -> 2
#define SWZ(vv) __builtin_bit_cast(f16x2,                                     \
            __builtin_amdgcn_ds_swizzle(__builtin_bit_cast(int, vv), 0x101F))
        f16x2 s0 = SWZ(P0), s1 = SWZ(P1), s2 = SWZ(P2), s3 = SWZ(P3);
#undef SWZ
        const bool hi4 = (kg & 4) != 0;
        f16x2 A = (hi4 ? P2 : P0) + (hi4 ? s2 : s0);
        f16x2 B = (hi4 ? P3 : P1) + (hi4 ? s3 : s1);
        // round 2: xor2 via DPP quad_perm [2,3,0,1]=0x4E, narrow 2 -> 1
        A = A + dpp_qp<0x4E>(A);
        B = B + dpp_qp<0x4E>(B);
        f16x2 C = (kg & 2) ? B : A;
        // round 3: xor1 via DPP quad_perm [1,0,3,2]=0xB1
        C = C + dpp_qp<0xB1>(C);
        float z = (float)((kg & 1) ? C.y : C.x) + u_cur;

        // tanh(z) = 1 - 2/(exp(2z)+1)
        float e2 = __expf(2.f * z);
        float r = 1.f - 2.f * __builtin_amdgcn_rcpf(e2 + 1.f);
        h_prev = 0.8f * h_prev + 0.2f * r;
        f16 hh = (f16)h_prev;

        h_pad[(t + 1) & 1][kg][cg] = hh;     // next step's input
        io[(size_t)t * H_DIM] = hh;          // hs[b][t][c] overwrites u slot
        u_cur = (float)u_next;
        __syncthreads();
    }
}

// ---------------------------------------------------------------------------
// Phase 3: out[row][o] = sum_k hs[row][k] * Who[k][o], K=512, O=64, fp32 out.
// ---------------------------------------------------------------------------
__global__ __launch_bounds__(256)
void out_gemm_kernel(const f16* __restrict__ hs, const float* __restrict__ Who,
                     float* __restrict__ out) {
    const int tid = threadIdx.x;
    const int r0 = blockIdx.x * 32;

    __shared__ __align__(16) f16x2 who_s[128][O_DIM];
    __shared__ __align__(16) f16x2 hs_s[32][128];

    const int o = tid & 63;
    const int rg = tid >> 6;

    float acc[8];
#pragma unroll
    for (int r = 0; r < 8; ++r) acc[r] = 0.f;

    for (int kc = 0; kc < 2; ++kc) {
        if (kc) __syncthreads();
#pragma unroll
        for (int i = 0; i < 32; ++i) {
            int idx = i * 256 + tid;
            int kp = idx >> 6;
            int oc = idx & 63;
            float w0 = Who[(size_t)(kc * 256 + 2 * kp + 0) * O_DIM + oc];
            float w1 = Who[(size_t)(kc * 256 + 2 * kp + 1) * O_DIM + oc];
            f16x2 w; w.x = (f16)w0; w.y = (f16)w1;
            who_s[kp][oc] = w;
        }
        f16x8* hd = (f16x8*)hs_s;
#pragma unroll
        for (int i = 0; i < 4; ++i) {
            int idx = i * 256 + tid;
            int r = idx >> 5;
            int m = idx & 31;
            f16x8 v = *(const f16x8*)(hs + (size_t)(r0 + r) * H_DIM + kc * 256 + m * 8);
            hd[idx] = v;
        }
        __syncthreads();

#pragma unroll
        for (int sc = 0; sc < 4; ++sc) {
            f16x2 wv[32];
#pragma unroll
            for (int i = 0; i < 32; ++i) wv[i] = who_s[sc * 32 + i][o];
#pragma unroll
            for (int r = 0; r < 8; ++r) {
                const int row = rg * 8 + r;
#pragma unroll
                for (int m = 0; m < 8; ++m) {
                    f16x8 h8 = *(const f16x8*)(&hs_s[row][sc * 32 + 4 * m]);
                    const f16x2* hp = (const f16x2*)&h8;
                    acc[r] = fdot2f(wv[4 * m + 0], hp[0], acc[r]);
                    acc[r] = fdot2f(wv[4 * m + 1], hp[1], acc[r]);
                    acc[r] = fdot2f(wv[4 * m + 2], hp[2], acc[r]);
                    acc[r] = fdot2f(wv[4 * m + 3], hp[3], acc[r]);
                }
            }
        }
    }
#pragma unroll
    for (int r = 0; r < 8; ++r) {
        int row = r0 + rg * 8 + r;
        out[(size_t)row * O_DIM + o] = acc[r];
    }
}

extern "C" void kernel_launch(void* const* d_in, const int* in_sizes, int n_in,
                              void* d_out, int out_size, void* d_ws, size_t ws_size,
                              hipStream_t stream) {
    const float* x    = (const float*)d_in[0];   // [64][2048][128]
    const float* Wih  = (const float*)d_in[1];   // [128][512]
    const float* Wrec = (const float*)d_in[2];   // [512][512]
    const float* Who  = (const float*)d_in[3];   // [512][64]
    float* out = (float*)d_out;                  // [64][2048][64]
    f16* uhs = (f16*)d_ws;                       // 128 MB: u, then hs in-place

    const int R = BATCH * S_LEN;

    u_gemm_kernel<<<dim3(R / 32, H_DIM / 128), 256, 0, stream>>>(x, Wih, uhs);
    rnn_scan_kernel<<<dim3(BATCH), 512, 0, stream>>>(Wrec, uhs);
    out_gemm_kernel<<<dim3(R / 32), 256, 0, stream>>>(uhs, Who, out);
}

// Round 5
// 3310.012 us; speedup vs baseline: 19.6353x; 1.0802x over previous
//
#include <hip/hip_runtime.h>
#include <hip/hip_fp16.h>
#include <cstdint>
#include <cstddef>

typedef _Float16 f16;
typedef _Float16 f16x2 __attribute__((ext_vector_type(2)));
typedef _Float16 f16x4 __attribute__((ext_vector_type(4)));
typedef _Float16 f16x8 __attribute__((ext_vector_type(8)));

#define S_LEN 2048
#define BATCH 64
#define I_DIM 128
#define H_DIM 512
#define O_DIM 64

// v_dot2_f32_f16 (fp32 accumulate — used in the small GEMMs only).
__device__ __forceinline__ float fdot2f(f16x2 a, f16x2 b, float c) {
#if __has_builtin(__builtin_amdgcn_fdot2)
    return __builtin_amdgcn_fdot2(a, b, c, false);
#else
    return c + (float)a.x * (float)b.x + (float)a.y * (float)b.y;
#endif
}

// v_pk_fma_f16: packed f16 FMA.
__device__ __forceinline__ f16x2 pkfma(f16x2 a, f16x2 b, f16x2 c) {
    __half2 r = __hfma2(__builtin_bit_cast(__half2, a),
                        __builtin_bit_cast(__half2, b),
                        __builtin_bit_cast(__half2, c));
    return __builtin_bit_cast(f16x2, r);
}

// DPP quad_perm cross-lane (xor1: 0xB1, xor2: 0x4E) — VALU, no LDS.
template <int CTRL>
__device__ __forceinline__ f16x2 dpp_qp(f16x2 v) {
    int r = __builtin_amdgcn_update_dpp(0, __builtin_bit_cast(int, v),
                                        CTRL, 0xF, 0xF, true);
    return __builtin_bit_cast(f16x2, r);
}

// ---------------------------------------------------------------------------
// Phase 1: u[row][c] = sum_k x[row][k] * Wih[k][c], rows = B*S, K=128, N=512.
// ---------------------------------------------------------------------------
__global__ __launch_bounds__(256)
void u_gemm_kernel(const float* __restrict__ x, const float* __restrict__ Wih,
                   f16* __restrict__ u) {
    const int tid = threadIdx.x;
    const int r0 = blockIdx.x * 32;
    const int c0 = blockIdx.y * 128;

    __shared__ __align__(16) f16x2 wih_s[I_DIM / 2][128];
    __shared__ __align__(16) f16x2 x_s[32][I_DIM / 2];

#pragma unroll
    for (int i = 0; i < 32; ++i) {
        int idx = i * 256 + tid;
        int kp = idx >> 7;
        int cl = idx & 127;
        float w0 = Wih[(size_t)(2 * kp + 0) * H_DIM + c0 + cl];
        float w1 = Wih[(size_t)(2 * kp + 1) * H_DIM + c0 + cl];
        f16x2 w; w.x = (f16)w0; w.y = (f16)w1;
        wih_s[kp][cl] = w;
    }
    const float4* xs = (const float4*)(x + (size_t)r0 * I_DIM);
    f16x4* xd = (f16x4*)x_s;
#pragma unroll
    for (int i = 0; i < 4; ++i) {
        int idx = i * 256 + tid;
        float4 v = xs[idx];
        f16x4 h; h.x = (f16)v.x; h.y = (f16)v.y; h.z = (f16)v.z; h.w = (f16)v.w;
        xd[idx] = h;
    }
    __syncthreads();

    const int cl = tid & 127;
    const int rh = tid >> 7;
    float acc[16];
#pragma unroll
    for (int r = 0; r < 16; ++r) acc[r] = 0.f;

#pragma unroll
    for (int kc = 0; kc < 2; ++kc) {
        f16x2 wv[32];
#pragma unroll
        for (int i = 0; i < 32; ++i) wv[i] = wih_s[kc * 32 + i][cl];
#pragma unroll
        for (int r = 0; r < 16; ++r) {
            const int row = rh * 16 + r;
#pragma unroll
            for (int m = 0; m < 8; ++m) {
                f16x8 h8 = *(const f16x8*)(&x_s[row][kc * 32 + 4 * m]);
                const f16x2* hp = (const f16x2*)&h8;
                acc[r] = fdot2f(wv[4 * m + 0], hp[0], acc[r]);
                acc[r] = fdot2f(wv[4 * m + 1], hp[1], acc[r]);
                acc[r] = fdot2f(wv[4 * m + 2], hp[2], acc[r]);
                acc[r] = fdot2f(wv[4 * m + 3], hp[3], acc[r]);
            }
        }
    }
#pragma unroll
    for (int r = 0; r < 16; ++r) {
        int row = r0 + rh * 16 + r;
        u[(size_t)row * H_DIM + c0 + cl] = (f16)acc[r];
    }
}

// ---------------------------------------------------------------------------
// Phase 2: split-K scan, one WG (512 threads) per batch, CU-local.
// Thread (kg=tid&7, cg=tid>>3) owns k-slice [kg*64,kg*64+64) of columns
// c=i*64+cg (i=0..7).
// Register budget is the whole game: W/thread = 256 f16x2 pairs but the
// per-wave cap at 8 waves/CU is 256 regs TOTAL (V+A unified on gfx950).
// R2/R4 let the compiler split 128 V + 128 A -> hot-loop scratch spills
// (~45 MB/launch of extra WRITE_SIZE). Fix: declare only 216 W-pairs
// (cols 0..5 full + col6 pairs 0..23) so W + ~34-reg working set fits in
// pure VGPRs; the other 40 pairs (col6 pairs 24..31 + col7) live in LDS
// (10 x ds_read_b128 per thread per step, 80 KB).
// ---------------------------------------------------------------------------
__global__ __launch_bounds__(512, 2)
void rnn_scan_kernel(const float* __restrict__ Wrec, f16* __restrict__ uhs) {
    const int tid = threadIdx.x;
    const int b = blockIdx.x;
    const int kg = tid & 7;
    const int cg = tid >> 3;
    const int k0 = kg * 64;

    __shared__ __align__(16) f16x8 wl[10][512];    // 40 pairs/thread: 81920 B
    __shared__ __align__(16) f16 h_pad[2][8][72];  // 64 data + 8 pad: 2304 B

    // ---- W in VGPRs: cols i*64+cg (i=0..5) all 32 pairs, col6 pairs 0..23 ----
    f16x2 wreg[6][32];
#pragma unroll
    for (int i = 0; i < 6; ++i)
#pragma unroll
        for (int p = 0; p < 32; ++p) {
            float a = Wrec[(size_t)(k0 + 2 * p + 0) * H_DIM + i * 64 + cg];
            float c = Wrec[(size_t)(k0 + 2 * p + 1) * H_DIM + i * 64 + cg];
            f16x2 w; w.x = (f16)a; w.y = (f16)c;
            wreg[i][p] = w;
        }
    f16x2 w6reg[24];
#pragma unroll
    for (int p = 0; p < 24; ++p) {
        float a = Wrec[(size_t)(k0 + 2 * p + 0) * H_DIM + 384 + cg];
        float c = Wrec[(size_t)(k0 + 2 * p + 1) * H_DIM + 384 + cg];
        f16x2 w; w.x = (f16)a; w.y = (f16)c;
        w6reg[p] = w;
    }
    // ---- W in LDS: q=0,1 -> col6 pairs 24..31; q=2..9 -> col7 pairs 0..31 ----
#pragma unroll
    for (int q = 0; q < 2; ++q) {
        f16x8 v;
#pragma unroll
        for (int e = 0; e < 8; ++e)
            v[e] = (f16)Wrec[(size_t)(k0 + 48 + 8 * q + e) * H_DIM + 384 + cg];
        wl[q][tid] = v;
    }
#pragma unroll
    for (int q = 2; q < 10; ++q) {
        f16x8 v;
#pragma unroll
        for (int e = 0; e < 8; ++e)
            v[e] = (f16)Wrec[(size_t)(k0 + 8 * (q - 2) + e) * H_DIM + 448 + cg];
        wl[q][tid] = v;
    }
    if (tid < 576) ((f16*)h_pad)[tid] = (f16)0.f;   // zero h buffer 0
    __syncthreads();

    const int c_own = k0 + cg;
    f16* io = uhs + (size_t)b * S_LEN * H_DIM + c_own;
    float h_prev = 0.f;
    float u_cur = (float)io[0];

    const f16* hb0 = &h_pad[0][kg][0];
    const f16* hb1 = &h_pad[1][kg][0];

    for (int t = 0; t < S_LEN; ++t) {
        f16 u_next = (f16)0.f;
        if (t + 1 < S_LEN) u_next = io[(size_t)(t + 1) * H_DIM];

        const f16* hb = (t & 1) ? hb1 : hb0;
        f16x2 acc[8];
#pragma unroll
        for (int i = 0; i < 8; ++i) { acc[i].x = (f16)0.f; acc[i].y = (f16)0.f; }

#pragma unroll
        for (int g = 0; g < 8; ++g) {
            f16x8 hv = *(const f16x8*)(hb + g * 8);   // 8-addr broadcast b128
            f16x8 w7v = wl[2 + g][tid];               // col7 pairs 4g..4g+3
            f16x8 w6v;
            if (g >= 6) w6v = wl[g - 6][tid];         // col6 pairs 24..31
            const f16x2* hp = (const f16x2*)&hv;
            const f16x2* w7p = (const f16x2*)&w7v;
            const f16x2* w6p = (const f16x2*)&w6v;
#pragma unroll
            for (int p = 0; p < 4; ++p) {
                acc[0] = pkfma(wreg[0][g * 4 + p], hp[p], acc[0]);
                acc[1] = pkfma(wreg[1][g * 4 + p], hp[p], acc[1]);
                acc[2] = pkfma(wreg[2][g * 4 + p], hp[p], acc[2]);
                acc[3] = pkfma(wreg[3][g * 4 + p], hp[p], acc[3]);
                acc[4] = pkfma(wreg[4][g * 4 + p], hp[p], acc[4]);
                acc[5] = pkfma(wreg[5][g * 4 + p], hp[p], acc[5]);
                acc[6] = pkfma(g < 6 ? w6reg[g * 4 + p] : w6p[p], hp[p], acc[6]);
                acc[7] = pkfma(w7p[p], hp[p], acc[7]);
            }
        }

        // compress each column (even-k + odd-k halves) and pack column pairs
        f16x2 P0, P1, P2, P3;
        P0.x = acc[0].x + acc[0].y;  P0.y = acc[1].x + acc[1].y;
        P1.x = acc[2].x + acc[2].y;  P1.y = acc[3].x + acc[3].y;
        P2.x = acc[4].x + acc[4].y;  P2.y = acc[5].x + acc[5].y;
        P3.x = acc[6].x + acc[6].y;  P3.y = acc[7].x + acc[7].y;

        // round 1: xor4 via ds_swizzle, narrow 4 vecs -> 2
#define SWZ(vv) __builtin_bit_cast(f16x2,                                     \
            __builtin_amdgcn_ds_swizzle(__builtin_bit_cast(int, vv), 0x101F))
        f16x2 s0 = SWZ(P0), s1 = SWZ(P1), s2 = SWZ(P2), s3 = SWZ(P3);
#undef SWZ
        const bool hi4 = (kg & 4) != 0;
        f16x2 A = (hi4 ? P2 : P0) + (hi4 ? s2 : s0);
        f16x2 B = (hi4 ? P3 : P1) + (hi4 ? s3 : s1);
        // round 2: xor2 via DPP quad_perm [2,3,0,1]=0x4E, narrow 2 -> 1
        A = A + dpp_qp<0x4E>(A);
        B = B + dpp_qp<0x4E>(B);
        f16x2 C = (kg & 2) ? B : A;
        // round 3: xor1 via DPP quad_perm [1,0,3,2]=0xB1
        C = C + dpp_qp<0xB1>(C);
        float z = (float)((kg & 1) ? C.y : C.x) + u_cur;

        // tanh(z) = 1 - 2/(exp(2z)+1)
        float e2 = __expf(2.f * z);
        float r = 1.f - 2.f * __builtin_amdgcn_rcpf(e2 + 1.f);
        h_prev = 0.8f * h_prev + 0.2f * r;
        f16 hh = (f16)h_prev;

        h_pad[(t + 1) & 1][kg][cg] = hh;     // next step's input
        io[(size_t)t * H_DIM] = hh;          // hs[b][t][c] overwrites u slot
        u_cur = (float)u_next;
        __syncthreads();
    }
}

// ---------------------------------------------------------------------------
// Phase 3: out[row][o] = sum_k hs[row][k] * Who[k][o], K=512, O=64, fp32 out.
// ---------------------------------------------------------------------------
__global__ __launch_bounds__(256)
void out_gemm_kernel(const f16* __restrict__ hs, const float* __restrict__ Who,
                     float* __restrict__ out) {
    const int tid = threadIdx.x;
    const int r0 = blockIdx.x * 32;

    __shared__ __align__(16) f16x2 who_s[128][O_DIM];
    __shared__ __align__(16) f16x2 hs_s[32][128];

    const int o = tid & 63;
    const int rg = tid >> 6;

    float acc[8];
#pragma unroll
    for (int r = 0; r < 8; ++r) acc[r] = 0.f;

    for (int kc = 0; kc < 2; ++kc) {
        if (kc) __syncthreads();
#pragma unroll
        for (int i = 0; i < 32; ++i) {
            int idx = i * 256 + tid;
            int kp = idx >> 6;
            int oc = idx & 63;
            float w0 = Who[(size_t)(kc * 256 + 2 * kp + 0) * O_DIM + oc];
            float w1 = Who[(size_t)(kc * 256 + 2 * kp + 1) * O_DIM + oc];
            f16x2 w; w.x = (f16)w0; w.y = (f16)w1;
            who_s[kp][oc] = w;
        }
        f16x8* hd = (f16x8*)hs_s;
#pragma unroll
        for (int i = 0; i < 4; ++i) {
            int idx = i * 256 + tid;
            int r = idx >> 5;
            int m = idx & 31;
            f16x8 v = *(const f16x8*)(hs + (size_t)(r0 + r) * H_DIM + kc * 256 + m * 8);
            hd[idx] = v;
        }
        __syncthreads();

#pragma unroll
        for (int sc = 0; sc < 4; ++sc) {
            f16x2 wv[32];
#pragma unroll
            for (int i = 0; i < 32; ++i) wv[i] = who_s[sc * 32 + i][o];
#pragma unroll
            for (int r = 0; r < 8; ++r) {
                const int row = rg * 8 + r;
#pragma unroll
                for (int m = 0; m < 8; ++m) {
                    f16x8 h8 = *(const f16x8*)(&hs_s[row][sc * 32 + 4 * m]);
                    const f16x2* hp = (const f16x2*)&h8;
                    acc[r] = fdot2f(wv[4 * m + 0], hp[0], acc[r]);
                    acc[r] = fdot2f(wv[4 * m + 1], hp[1], acc[r]);
                    acc[r] = fdot2f(wv[4 * m + 2], hp[2], acc[r]);
                    acc[r] = fdot2f(wv[4 * m + 3], hp[3], acc[r]);
                }
            }
        }
    }
#pragma unroll
    for (int r = 0; r < 8; ++r) {
        int row = r0 + rg * 8 + r;
        out[(size_t)row * O_DIM + o] = acc[r];
    }
}

extern "C" void kernel_launch(void* const* d_in, const int* in_sizes, int n_in,
                              void* d_out, int out_size, void* d_ws, size_t ws_size,
                              hipStream_t stream) {
    const float* x    = (const float*)d_in[0];   // [64][2048][128]
    const float* Wih  = (const float*)d_in[1];   // [128][512]
    const float* Wrec = (const float*)d_in[2];   // [512][512]
    const float* Who  = (const float*)d_in[3];   // [512][64]
    float* out = (float*)d_out;                  // [64][2048][64]
    f16* uhs = (f16*)d_ws;                       // 128 MB: u, then hs in-place

    const int R = BATCH * S_LEN;

    u_gemm_kernel<<<dim3(R / 32, H_DIM / 128), 256, 0, stream>>>(x, Wih, uhs);
    rnn_scan_kernel<<<dim3(BATCH), 512, 0, stream>>>(Wrec, uhs);
    out_gemm_kernel<<<dim3(R / 32), 256, 0, stream>>>(uhs, Who, out);
}